// Round 9
// baseline (116.030 us; speedup 1.0000x reference)
//
#include <hip/hip_runtime.h>

typedef float v2f __attribute__((ext_vector_type(2)));
typedef float v4f __attribute__((ext_vector_type(4)));

// ---------------------------------------------------------------------------
// Layout (8 px/wave): group g = lane>>4 holds the packed pixel pair in v2f.
// Amp i = q*16 + r, q = lane&15, r = 0..15. Wires 0..3 <-> q bits 3..0
// (masks 8,4,2,1); wires 4..7 <-> r bits 3..0.
// Round-9 (on top of R8): DPP BATCHING. Every DPP-consuming stage hoists all
// 64 butterfly DPP reads into named temps, pins them with
// sched_barrier(0), then runs the FMA bodies. Rationale: DPP ops carry
// HW wait-states on the VALU-write->DPP-read and DPP-write->VALU-read
// edges; per-r "DPP then FMA" codegen exposes them ~2200x per wave. Batched
// independent DPPs absorb each other's wait states. The barrier prevents
// the scheduler from re-sinking the hoist (R7/R8 failure mode: scheduler's
// latency model re-sinks anything hoisted, VGPR stayed 96).
// Tripwires: VGPR should RISE to ~150-200; WRITE_SIZE must stay 2048.
// ---------------------------------------------------------------------------
template<int C>
__device__ __forceinline__ float dppmov(float x) {
  return __int_as_float(__builtin_amdgcn_update_dpp(0, __float_as_int(x), C, 0xF, 0xF, true));
}
__device__ __forceinline__ float bperm(float x, int a) {
  return __int_as_float(__builtin_amdgcn_ds_bpermute(a, __float_as_int(x)));
}
template<int M>
__device__ __forceinline__ float bfly(float x) {
  if constexpr (M == 1)      return dppmov<0xB1>(x);   // quad_perm [1,0,3,2]
  else if constexpr (M == 2) return dppmov<0x4E>(x);   // quad_perm [2,3,0,1]
  else if constexpr (M == 3) return dppmov<0x1B>(x);   // quad_perm [3,2,1,0]
  else if constexpr (M == 8) return dppmov<0x128>(x);  // row_ror:8 == xor8
  else                       return dppmov<0x1B>(dppmov<0x141>(x)); // xor4 = xor7 o xor3
}
template<int M>
__device__ __forceinline__ v2f bfly2(v2f v) {
  v2f o; o.x = bfly<M>(v.x); o.y = bfly<M>(v.y); return o;
}
__device__ __forceinline__ v2f sp(float s) { v2f v; v.x = s; v.y = s; return v; }
__device__ __forceinline__ v2f vfma(v2f a, v2f b, v2f c) {
  return __builtin_elementwise_fma(a, b, c);
}

// ---------------------------------------------------------------------------
// Gate stages (16 state regs). Coefficients arrive as v4f VALUES.
// DPP-batched: hoist all partner reads, pin, then FMA.
// ---------------------------------------------------------------------------
template<int M>
__device__ __forceinline__ void crossGv(v2f Sr[16], v2f Si[16], v4f c) {
  v2f vfr = sp(c.x), vfi = sp(c.y), vgr = sp(c.z), vgi = sp(c.w);
  v2f vfiN = sp(-c.y), vgiN = sp(-c.w);
  v2f pR[16], pI[16];
#pragma unroll
  for (int r = 0; r < 16; ++r) {
    pR[r] = bfly2<M>(Sr[r]);
    pI[r] = bfly2<M>(Si[r]);
  }
  __builtin_amdgcn_sched_barrier(0);
#pragma unroll
  for (int r = 0; r < 16; ++r) {
    v2f nR = vfma(vgiN, pI[r], vfma(vgr, pR[r], vfma(vfiN, Si[r], vfr * Sr[r])));
    v2f nI = vfma(vgi,  pR[r], vfma(vgr, pI[r], vfma(vfi,  Sr[r], vfr * Si[r])));
    Sr[r] = nR; Si[r] = nI;
  }
}

__device__ __forceinline__ void mixP(v2f& x0r, v2f& x0i, v2f& x1r, v2f& x1i,
    float m0r, float m0i, float m1r, float m1i,
    float m2r, float m2i, float m3r, float m3i) {
  v2f n0r = vfma(sp(-m1i), x1i, vfma(sp(m1r), x1r, vfma(sp(-m0i), x0i, sp(m0r) * x0r)));
  v2f n0i = vfma(sp( m1i), x1r, vfma(sp(m1r), x1i, vfma(sp( m0i), x0r, sp(m0r) * x0i)));
  v2f n1r = vfma(sp(-m3i), x1i, vfma(sp(m3r), x1r, vfma(sp(-m2i), x0i, sp(m2r) * x0r)));
  v2f n1i = vfma(sp( m3i), x1r, vfma(sp(m3r), x1i, vfma(sp( m2i), x0r, sp(m2r) * x0i)));
  x0r = n0r; x0i = n0i; x1r = n1r; x1i = n1i;
}

// F4: fused u3(w4)+cu3(3->4): ctrl lane bit0 (baked into address), tgt r bit3.
__device__ __forceinline__ void f4Nv(v2f Sr[16], v2f Si[16], v4f A, v4f B) {
#pragma unroll
  for (int r = 0; r < 8; ++r)
    mixP(Sr[r], Si[r], Sr[r + 8], Si[r + 8],
         A.x, A.y, A.z, A.w, B.x, B.y, B.z, B.w);
}
// F5: ctrl r bit3, target r bit2 (uniform; coeffs pre-loaded by caller).
__device__ __forceinline__ void f5v(v2f Sr[16], v2f Si[16],
    v4f A, v4f B, v4f C, v4f D) {
#pragma unroll
  for (int r = 0; r < 4; ++r)
    mixP(Sr[r], Si[r], Sr[r + 4], Si[r + 4],
         A.x, A.y, A.z, A.w, B.x, B.y, B.z, B.w);
#pragma unroll
  for (int r = 8; r < 12; ++r)
    mixP(Sr[r], Si[r], Sr[r + 4], Si[r + 4],
         C.x, C.y, C.z, C.w, D.x, D.y, D.z, D.w);
}

// One row of the F67 4x4: d = M[row] . a, M row = {a.x..a.w, b.x..b.w}.
__device__ __forceinline__ void f67row(v2f& dR, v2f& dI, v4f a, v4f b,
    v2f ar0, v2f ai0, v2f ar1, v2f ai1,
    v2f ar2, v2f ai2, v2f ar3, v2f ai3) {
  v2f nR = sp(a.x) * ar0;
  nR = vfma(sp(-a.y), ai0, nR);
  nR = vfma(sp( a.z), ar1, nR);
  nR = vfma(sp(-a.w), ai1, nR);
  nR = vfma(sp( b.x), ar2, nR);
  nR = vfma(sp(-b.y), ai2, nR);
  nR = vfma(sp( b.z), ar3, nR);
  nR = vfma(sp(-b.w), ai3, nR);
  v2f nI = sp(a.y) * ar0;
  nI = vfma(sp(a.x), ai0, nI);
  nI = vfma(sp(a.w), ar1, nI);
  nI = vfma(sp(a.z), ai1, nI);
  nI = vfma(sp(b.y), ar2, nI);
  nI = vfma(sp(b.x), ai2, nI);
  nI = vfma(sp(b.w), ar3, nI);
  nI = vfma(sp(b.z), ai3, nI);
  dR = nR; dI = nI;
}
// F67 4x4 on one reg-quad at base B; rows (m0a,m0b)..(m3a,m3b).
__device__ __forceinline__ void f67q(v2f* Sr, v2f* Si, int B,
    v4f m0a, v4f m0b, v4f m1a, v4f m1b,
    v4f m2a, v4f m2b, v4f m3a, v4f m3b) {
  v2f ar0 = Sr[B+0], ai0 = Si[B+0], ar1 = Sr[B+1], ai1 = Si[B+1];
  v2f ar2 = Sr[B+2], ai2 = Si[B+2], ar3 = Sr[B+3], ai3 = Si[B+3];
  f67row(Sr[B+0], Si[B+0], m0a, m0b, ar0, ai0, ar1, ai1, ar2, ai2, ar3, ai3);
  f67row(Sr[B+1], Si[B+1], m1a, m1b, ar0, ai0, ar1, ai1, ar2, ai2, ar3, ai3);
  f67row(Sr[B+2], Si[B+2], m2a, m2b, ar0, ai0, ar1, ai1, ar2, ai2, ar3, ai3);
  f67row(Sr[B+3], Si[B+3], m3a, m3b, ar0, ai0, ar1, ai1, ar2, ai2, ar3, ai3);
}

// F8': fused cu3(7->0)+next u3(w0): ctrl r bit0, target mask 8. DPP-batched.
__device__ __forceinline__ void f8pNv(v2f Sr[16], v2f Si[16], v4f A, v4f B) {
  v2f pR[16], pI[16];
#pragma unroll
  for (int r = 0; r < 16; ++r) {
    pR[r] = bfly2<8>(Sr[r]);
    pI[r] = bfly2<8>(Si[r]);
  }
  __builtin_amdgcn_sched_barrier(0);
  {
    v2f fr = sp(A.x), fi = sp(A.y), gr = sp(A.z), gi = sp(A.w);
    v2f fiN = sp(-A.y), giN = sp(-A.w);
#pragma unroll
    for (int r = 0; r < 16; r += 2) {
      v2f nR = vfma(giN, pI[r], vfma(gr, pR[r], vfma(fiN, Si[r], fr * Sr[r])));
      v2f nI = vfma(gi,  pR[r], vfma(gr, pI[r], vfma(fi,  Sr[r], fr * Si[r])));
      Sr[r] = nR; Si[r] = nI;
    }
  }
  {
    v2f fr = sp(B.x), fi = sp(B.y), gr = sp(B.z), gi = sp(B.w);
    v2f fiN = sp(-B.y), giN = sp(-B.w);
#pragma unroll
    for (int r = 1; r < 16; r += 2) {
      v2f nR = vfma(giN, pI[r], vfma(gr, pR[r], vfma(fiN, Si[r], fr * Sr[r])));
      v2f nI = vfma(gi,  pR[r], vfma(gr, pI[r], vfma(fi,  Sr[r], fr * Si[r])));
      Sr[r] = nR; Si[r] = nI;
    }
  }
}
// F8 final standalone cu3(7->0): odd r only, target mask 8. DPP-batched.
__device__ __forceinline__ void f8Nv(v2f Sr[16], v2f Si[16], v4f c) {
  v2f vfr = sp(c.x), vfi = sp(c.y), vgr = sp(c.z), vgi = sp(c.w);
  v2f vfiN = sp(-c.y), vgiN = sp(-c.w);
  v2f pR[8], pI[8];
#pragma unroll
  for (int r = 1; r < 16; r += 2) {
    pR[r >> 1] = bfly2<8>(Sr[r]);
    pI[r >> 1] = bfly2<8>(Si[r]);
  }
  __builtin_amdgcn_sched_barrier(0);
#pragma unroll
  for (int r = 1; r < 16; r += 2) {
    v2f nR = vfma(vgiN, pI[r >> 1], vfma(vgr, pR[r >> 1], vfma(vfiN, Si[r], vfr * Sr[r])));
    v2f nI = vfma(vgi,  pR[r >> 1], vfma(vgr, pI[r >> 1], vfma(vfi,  Sr[r], vfr * Si[r])));
    Sr[r] = nR; Si[r] = nI;
  }
}

// Off-diagonal pair sum for a cross wire (mask M): per-lane partials.
// DPP-batched; dual accumulators widen the serial chains.
template<int M>
__device__ __forceinline__ void crossO(const v2f Sr[16], const v2f Si[16],
                                       v2f& re, v2f& im) {
  v2f pr[16], pi[16];
#pragma unroll
  for (int k = 0; k < 16; ++k) {
    pr[k] = bfly2<M>(Sr[k]);
    pi[k] = bfly2<M>(Si[k]);
  }
  __builtin_amdgcn_sched_barrier(0);
  v2f r0 = sp(0.0f), r1 = sp(0.0f), i0 = sp(0.0f), i1 = sp(0.0f);
#pragma unroll
  for (int k = 0; k < 16; k += 2) {
    r0 = vfma(Sr[k], pr[k], r0);
    r0 = vfma(Si[k], pi[k], r0);
    i0 = vfma(Si[k], pr[k], i0);
    i0 = vfma(-Sr[k], pi[k], i0);
    r1 = vfma(Sr[k+1], pr[k+1], r1);
    r1 = vfma(Si[k+1], pi[k+1], r1);
    i1 = vfma(Si[k+1], pr[k+1], i1);
    i1 = vfma(-Sr[k+1], pi[k+1], i1);
  }
  re = r0 + r1; im = i0 + i1;
}

// ---------------------------------------------------------------------------
// Prep helpers.
// ---------------------------------------------------------------------------
__device__ __forceinline__ void mm2(const float* A, const float* B, float* D) {
  D[0] = A[0]*B[0] - A[1]*B[1] + A[2]*B[4] - A[3]*B[5];
  D[1] = A[0]*B[1] + A[1]*B[0] + A[2]*B[5] + A[3]*B[4];
  D[2] = A[0]*B[2] - A[1]*B[3] + A[2]*B[6] - A[3]*B[7];
  D[3] = A[0]*B[3] + A[1]*B[2] + A[2]*B[7] + A[3]*B[6];
  D[4] = A[4]*B[0] - A[5]*B[1] + A[6]*B[4] - A[7]*B[5];
  D[5] = A[4]*B[1] + A[5]*B[0] + A[6]*B[5] + A[7]*B[4];
  D[6] = A[4]*B[2] - A[5]*B[3] + A[6]*B[6] - A[7]*B[7];
  D[7] = A[4]*B[3] + A[5]*B[2] + A[6]*B[7] + A[7]*B[6];
}
__device__ __forceinline__ void u3fill(const float* src, float* o) {
  float th = src[0], ph = src[1], lam = src[2];
  float c = cosf(0.5f * th), s = sinf(0.5f * th);
  float cl = cosf(lam), sl = sinf(lam);
  float cp = cosf(ph), spv = sinf(ph);
  float cpl = cosf(ph + lam), spl = sinf(ph + lam);
  o[0] = c;        o[1] = 0.0f;
  o[2] = -cl * s;  o[3] = -sl * s;
  o[4] = cp * s;   o[5] = spv * s;
  o[6] = cpl * c;  o[7] = spl * c;
}

// ---------------------------------------------------------------------------
// Single fused kernel. Gp layout (per block b, stride 80 floats):
//   +0  F1 [sel=ct*2+hi][4]={fr,fi,gr,gi}; +16 F2; +32 F3
//   +48 F4 [ct][8]; +64 F8' [hi][8]. Final F8 at Gp+400: [hi][4].
// ---------------------------------------------------------------------------
__global__ __launch_bounds__(256, 2) void qconv_kernel(
    const float* __restrict__ x, const float* __restrict__ cw,
    const float* __restrict__ cb, const float* __restrict__ u3p,
    const float* __restrict__ cu3p, const float* __restrict__ fcw,
    const float* __restrict__ fcb, float* __restrict__ out) {
  __shared__ float Us[40][8];
  __shared__ float Cs[40][8];
  __shared__ __attribute__((aligned(16))) float Gs[640];
  __shared__ float FCWs[32 * 29];   // stride 29: odd*4 bank step, conflict-free
  __shared__ __attribute__((aligned(16))) float F67t[320];
  __shared__ __attribute__((aligned(16))) float Gp[408];

  // ---- in-block prep ----
  {
    const int t = threadIdx.x;
    if (t < 40) u3fill(u3p + t * 3, Us[t]);
    if (t >= 64 && t < 104) u3fill(cu3p + (t - 64) * 3, Cs[t - 64]);
    for (int i = t; i < 32 * 29; i += 256) {
      int ch = i / 29, u = i - ch * 29;
      float v = 0.0f;
      if (u < 24) {
        float sc = (u >= 8 && (u & 7) >= 4) ? 2.0f : 1.0f;
        v = fcw[ch * 24 + u] * sc;
      }
      FCWs[i] = v;
    }
    __syncthreads();
    if (t == 0) {
#pragma unroll
      for (int j = 0; j < 8; ++j) Gs[j] = Us[0][j];
    } else if (t < 36) {
      int j = t - 1, b = j / 7, k = j % 7;
      float* dst = Gs + 8 + b * 112 + k * 16;
      const float* U = Us[b * 8 + k + 1];
      const float* C = Cs[b * 8 + k];
#pragma unroll
      for (int u = 0; u < 8; ++u) dst[u] = U[u];
      mm2(C, U, dst + 8);
    } else if (t < 40) {
      int b = t - 36;
      float* dst = Gs + 568 + b * 16;
      const float* U = Us[(b + 1) * 8];
      const float* C = Cs[b * 8 + 7];
#pragma unroll
      for (int u = 0; u < 8; ++u) dst[u] = U[u];
      mm2(U, C, dst + 8);
    } else if (t == 40) {
#pragma unroll
      for (int j = 0; j < 8; ++j) Gs[632 + j] = Cs[39][j];
    }
    __syncthreads();
    // F67 fused tables + per-lane table permute (disjoint thread ranges)
    if (t < 60) {
      // crossG entries: 5 blocks x 3 stages x 4 sels
      int b = t / 12, rem = t % 12;
      int st = rem >> 2, sel = rem & 3;
      int hi = sel & 1, ct = sel >> 1;
      const float* src = Gs + 8 + b * 112 + st * 16 + (ct ? 8 : 0);
      float* dst = Gp + b * 80 + st * 16 + sel * 4;
      dst[0] = src[hi ? 6 : 0]; dst[1] = src[hi ? 7 : 1];
      dst[2] = src[hi ? 4 : 2]; dst[3] = src[hi ? 5 : 3];
    } else if (t >= 64 && t < 104) {
      int u = t - 64;
      int b = u >> 3, idx = u & 7;
      int ct = idx >> 2, rp = idx & 3;
      const float* M6 = Gs + 8 + b * 112 + 80 + ct * 8;
      int b1p = rp >> 1, b0p = rp & 1;
      const float* M7 = Gs + 8 + b * 112 + 96 + b1p * 8;
      float* dst = F67t + b * 64 + ct * 32 + rp * 8;
#pragma unroll
      for (int c = 0; c < 4; ++c) {
        int b1 = c >> 1, b0 = c & 1;
        float a_r = M6[(b1p * 2 + b1) * 2], a_i = M6[(b1p * 2 + b1) * 2 + 1];
        float b_r = M7[(b0p * 2 + b0) * 2], b_i = M7[(b0p * 2 + b0) * 2 + 1];
        dst[c * 2]     = a_r * b_r - a_i * b_i;
        dst[c * 2 + 1] = a_r * b_i + a_i * b_r;
      }
    } else if (t >= 192 && t < 202) {
      // F4 copy: 5 blocks x 2 ct halves
      int u = t - 192, b = u >> 1, ct = u & 1;
      const float* src = Gs + 8 + b * 112 + 48 + ct * 8;
      float* dst = Gp + b * 80 + 48 + ct * 8;
#pragma unroll
      for (int j = 0; j < 8; ++j) dst[j] = src[j];
    } else if (t >= 208 && t < 216) {
      // F8' entries: 4 blocks x 2 hi
      int u = t - 208, b = u >> 1, hi = u & 1;
      const float* src = Gs + 568 + b * 16;
      float* dst = Gp + b * 80 + 64 + hi * 8;
      dst[0] = src[hi ? 6 : 0];     dst[1] = src[hi ? 7 : 1];
      dst[2] = src[hi ? 4 : 2];     dst[3] = src[hi ? 5 : 3];
      dst[4] = src[8 + (hi ? 6 : 0)]; dst[5] = src[8 + (hi ? 7 : 1)];
      dst[6] = src[8 + (hi ? 4 : 2)]; dst[7] = src[8 + (hi ? 5 : 3)];
    } else if (t >= 216 && t < 218) {
      // F8 final: 2 hi entries
      int hi = t - 216;
      const float* src = Gs + 632;
      float* dst = Gp + 400 + hi * 4;
      dst[0] = src[hi ? 6 : 0]; dst[1] = src[hi ? 7 : 1];
      dst[2] = src[hi ? 4 : 2]; dst[3] = src[hi ? 5 : 3];
    }
    __syncthreads();
  }

  const int lane = threadIdx.x & 63;
  const int wid = __builtin_amdgcn_readfirstlane(
      (int)((blockIdx.x * blockDim.x + threadIdx.x) >> 6));
  const int p0 = wid * 8;
  const int q = lane & 15;

  // ---- conv: lane = (px = lane>>3, oc = lane&7); boundary math hoisted ----
  float ang;
  {
    const int px = lane >> 3;
    const int oc = lane & 7;
    const int p  = p0 + px;
    const int b  = p >> 12;
    const int hh = (p >> 6) & 63;
    const int wim = p & 63;
    int offs[9];
    float okf[9];
#pragma unroll
    for (int kh = 0; kh < 3; ++kh) {
      int ih = hh + kh - 1;
      bool rok = (unsigned)ih < 64u;
      int ihc = rok ? ih : 0;
#pragma unroll
      for (int kw = 0; kw < 3; ++kw) {
        int iw = wim + kw - 1;
        bool ok = rok && ((unsigned)iw < 64u);
        int iwc = ((unsigned)iw < 64u) ? iw : 0;
        offs[kh * 3 + kw] = ihc * 64 + iwc;
        okf[kh * 3 + kw] = ok ? 1.0f : 0.0f;
      }
    }
    float acc = cb[oc];
    const float* wp0 = cw + oc * 144;
    const float* xp0 = x + b * 65536;
#pragma unroll 4
    for (int ic = 0; ic < 16; ++ic) {
      const float* wp = wp0 + ic * 9;
      const float* xp = xp0 + ic * 4096;
#pragma unroll
      for (int j = 0; j < 9; ++j)
        acc = fmaf(xp[offs[j]] * okf[j], wp[j], acc);
    }
    ang = acc;
  }

  // ---- gather 16 angles, build product state with F0 folded ----
  v2f Sr[16], Si[16];
  {
    const int gb = (lane & 48) << 2;
    float aA[8], aB[8];
#pragma unroll
    for (int w = 0; w < 8; ++w) {
      aA[w] = bperm(ang, gb + (w << 2));
      aB[w] = bperm(ang, gb + ((8 + w) << 2));
    }
    float cA[8], sA[8], cB[8], sB[8];
#pragma unroll
    for (int w = 0; w < 8; ++w) {
      __sincosf(0.5f * aA[w], &sA[w], &cA[w]);
      __sincosf(0.5f * aB[w], &sB[w], &cB[w]);
    }
    v2f c0; c0.x = cA[0]; c0.y = cB[0];
    v2f s0; s0.x = sA[0]; s0.y = sB[0];
    v2f c0r = vfma(sp(Gs[2]), s0, sp(Gs[0]) * c0);
    v2f c0i = vfma(sp(Gs[3]), s0, sp(Gs[1]) * c0);
    v2f s0r = vfma(sp(Gs[6]), s0, sp(Gs[4]) * c0);
    v2f s0i = vfma(sp(Gs[7]), s0, sp(Gs[5]) * c0);
    const bool w0 = (q & 8) != 0;
    v2f selR = w0 ? s0r : c0r;
    v2f selI = w0 ? s0i : c0i;
    float fA = ((q & 4) ? sA[1] : cA[1]) * ((q & 2) ? sA[2] : cA[2])
             * ((q & 1) ? sA[3] : cA[3]);
    float fB = ((q & 4) ? sB[1] : cB[1]) * ((q & 2) ? sB[2] : cB[2])
             * ((q & 1) ? sB[3] : cB[3]);
    v2f uu[4], vv[4];
    uu[0].x = cA[6]*cA[7]; uu[1].x = cA[6]*sA[7];
    uu[2].x = sA[6]*cA[7]; uu[3].x = sA[6]*sA[7];
    uu[0].y = cB[6]*cB[7]; uu[1].y = cB[6]*sB[7];
    uu[2].y = sB[6]*cB[7]; uu[3].y = sB[6]*sB[7];
    float vA0 = fA * cA[4], vA1 = fA * sA[4];
    float vB0 = fB * cB[4], vB1 = fB * sB[4];
    vv[0].x = vA0*cA[5]; vv[1].x = vA0*sA[5];
    vv[2].x = vA1*cA[5]; vv[3].x = vA1*sA[5];
    vv[0].y = vB0*cB[5]; vv[1].y = vB0*sB[5];
    vv[2].y = vB1*cB[5]; vv[3].y = vB1*sB[5];
#pragma unroll
    for (int r = 0; r < 16; ++r) {
      v2f base = vv[r >> 2] * uu[r & 3];
      Sr[r] = selR * base;
      Si[r] = selI * base;
    }
  }

  // ---- fused circuit: pipelined per-lane coefficient reads ----
  {
    const int s1 = ((lane & 8) ? 2 : 0) | ((lane & 4) ? 1 : 0);
    const int s2 = ((lane & 4) ? 2 : 0) | ((lane & 2) ? 1 : 0);
    const int s3 = ((lane & 2) ? 2 : 0) | ((lane & 1) ? 1 : 0);
    const float* pF1 = Gp + s1 * 4;
    const float* pF2 = Gp + 16 + s2 * 4;
    const float* pF3 = Gp + 32 + s3 * 4;
    const float* pF4 = Gp + 48 + (lane & 1) * 8;
    const float* pF8 = Gp + 64 + ((lane & 8) ? 8 : 0);
    // prologue: block-0 per-lane coeffs
    v4f k1 = *(const v4f*)pF1;
    v4f k2 = *(const v4f*)pF2;
    v4f k3 = *(const v4f*)pF3;
    v4f k4a = *(const v4f*)pF4,      k4b = *(const v4f*)(pF4 + 4);
    v4f k8a = *(const v4f*)pF8,      k8b = *(const v4f*)(pF8 + 4);
    for (int b = 0; b < 5; ++b) {
      const int o = b * 80;
      // uniform tables for THIS block
      const v4f* f5p = (const v4f*)(Gs + 8 + b * 112 + 64);
      v4f f5A = f5p[0], f5B = f5p[1], f5C = f5p[2], f5D = f5p[3];
      const v4f* Tp = (const v4f*)(F67t + b * 64);
      v4f t0 = Tp[0],  t1 = Tp[1],  t2 = Tp[2],  t3 = Tp[3];
      v4f t4 = Tp[4],  t5 = Tp[5],  t6 = Tp[6],  t7 = Tp[7];
      v4f t8 = Tp[8],  t9 = Tp[9],  t10 = Tp[10], t11 = Tp[11];
      v4f t12 = Tp[12], t13 = Tp[13], t14 = Tp[14], t15 = Tp[15];
      // NEXT block's per-lane coeffs (clamped offset on last iter)
      const int no = (b < 4) ? o + 80 : o;
      v4f n1 = *(const v4f*)(pF1 + no);
      v4f n2 = *(const v4f*)(pF2 + no);
      v4f n3 = *(const v4f*)(pF3 + no);
      v4f n4a = *(const v4f*)(pF4 + no), n4b = *(const v4f*)(pF4 + no + 4);
      v4f n8a = *(const v4f*)(pF8 + no), n8b = *(const v4f*)(pF8 + no + 4);

      crossGv<4>(Sr, Si, k1);                    // F1: tgt w1(m4)
      crossGv<2>(Sr, Si, k2);                    // F2: tgt w2(m2)
      crossGv<1>(Sr, Si, k3);                    // F3: tgt w3(m1)
      f4Nv(Sr, Si, k4a, k4b);                    // F4: tgt r3
      f5v(Sr, Si, f5A, f5B, f5C, f5D);           // F5: tgt r2
      f67q(Sr, Si, 0,  t0, t1, t2,  t3,  t4,  t5,  t6,  t7);
      f67q(Sr, Si, 4,  t8, t9, t10, t11, t12, t13, t14, t15);
      f67q(Sr, Si, 8,  t0, t1, t2,  t3,  t4,  t5,  t6,  t7);
      f67q(Sr, Si, 12, t8, t9, t10, t11, t12, t13, t14, t15);
      if (b < 4) f8pNv(Sr, Si, k8a, k8b);        // F8': tgt m8, ctrl r0
      k1 = n1; k2 = n2; k3 = n3; k4a = n4a; k4b = n4b; k8a = n8a; k8b = n8b;
    }
    f8Nv(Sr, Si, *(const v4f*)(Gp + 400 + ((lane & 8) ? 4 : 0)));
  }

  // ---- per-lane measurement partials ----
  float sg[4];
  sg[0] = (q & 8) ? -1.0f : 1.0f;
  sg[1] = (q & 4) ? -1.0f : 1.0f;
  sg[2] = (q & 2) ? -1.0f : 1.0f;
  sg[3] = (q & 1) ? -1.0f : 1.0f;

  v2f PT[24];
  {
    v2f re0, im0, re1, im1, re2, im2, re3, im3;
    crossO<8>(Sr, Si, re0, im0);
    crossO<4>(Sr, Si, re1, im1);
    crossO<2>(Sr, Si, re2, im2);
    crossO<1>(Sr, Si, re3, im3);
    PT[8]  = re0; PT[9]  = re1; PT[10] = re2; PT[11] = re3;
    PT[16] = sp(sg[0]) * im0; PT[17] = sp(sg[1]) * im1;
    PT[18] = sp(sg[2]) * im2; PT[19] = sp(sg[3]) * im3;

    v2f P[16];
#pragma unroll
    for (int r = 0; r < 16; ++r) P[r] = vfma(Si[r], Si[r], Sr[r] * Sr[r]);
    v2f t01[8];
#pragma unroll
    for (int k = 0; k < 8; ++k) t01[k] = P[2*k] + P[2*k+1];
    v2f q0 = t01[0] + t01[1], q1 = t01[2] + t01[3];
    v2f q2 = t01[4] + t01[5], q3 = t01[6] + t01[7];
    v2f h0 = q0 + q1, h1 = q2 + q3;
    v2f p  = h0 + h1;
    PT[4] = h0 - h1;
    PT[5] = (q0 - q1) + (q2 - q3);
    PT[6] = (t01[0]-t01[1]) + (t01[2]-t01[3])
          + (t01[4]-t01[5]) + (t01[6]-t01[7]);
    PT[7] = (P[0]-P[1]) + (P[2]-P[3]) + (P[4]-P[5]) + (P[6]-P[7])
          + (P[8]-P[9]) + (P[10]-P[11]) + (P[12]-P[13]) + (P[14]-P[15]);
    PT[0] = sp(sg[0]) * p; PT[1] = sp(sg[1]) * p;
    PT[2] = sp(sg[2]) * p; PT[3] = sp(sg[3]) * p;

    v2f re, im;
    re = sp(0.0f); im = sp(0.0f);
#pragma unroll
    for (int r = 0; r < 8; ++r) {
      re = vfma(Sr[r], Sr[r+8], re); re = vfma(Si[r], Si[r+8], re);
      im = vfma(Si[r], Sr[r+8], im); im = vfma(-Sr[r], Si[r+8], im);
    }
    PT[12] = re; PT[20] = im;
    re = sp(0.0f); im = sp(0.0f);
#pragma unroll
    for (int t = 0; t < 8; ++t) {
      const int lo = (t & 3) + (t >> 2) * 8;
      re = vfma(Sr[lo], Sr[lo+4], re); re = vfma(Si[lo], Si[lo+4], re);
      im = vfma(Si[lo], Sr[lo+4], im); im = vfma(-Sr[lo], Si[lo+4], im);
    }
    PT[13] = re; PT[21] = im;
    re = sp(0.0f); im = sp(0.0f);
#pragma unroll
    for (int t = 0; t < 8; ++t) {
      const int lo = (t & 1) + (t >> 1) * 4;
      re = vfma(Sr[lo], Sr[lo+2], re); re = vfma(Si[lo], Si[lo+2], re);
      im = vfma(Si[lo], Sr[lo+2], im); im = vfma(-Sr[lo], Si[lo+2], im);
    }
    PT[14] = re; PT[22] = im;
    re = sp(0.0f); im = sp(0.0f);
#pragma unroll
    for (int t = 0; t < 8; ++t) {
      const int lo = 2 * t;
      re = vfma(Sr[lo], Sr[lo+1], re); re = vfma(Si[lo], Si[lo+1], re);
      im = vfma(Si[lo], Sr[lo+1], im); im = vfma(-Sr[lo], Si[lo+1], im);
    }
    PT[15] = re; PT[23] = im;
  }

  // ---- group-reduce partials to uniform values, THEN per-channel FC ----
  const int j = q & 7;
  const bool isB = (q & 8) != 0;
  float mm[24];
#pragma unroll
  for (int t = 0; t < 24; ++t) {
    v2f v = PT[t] + bfly2<8>(PT[t]);   // pair over mask 8 (both pixels)
    float s = isB ? v.y : v.x;          // keep own pixel
    s += bfly<1>(s);
    s += bfly<2>(s);
    s += bfly<4>(s);                    // completes the 16-lane sum
    mm[t] = s;
  }

  const int g = lane >> 4;
  const int p = p0 + 2 * g + (isB ? 1 : 0);
  const int ob = (p >> 12) * 131072 + (p & 4095);
#pragma unroll
  for (int k = 0; k < 4; ++k) {
    const int ch = 4 * j + k;
    const float* wr = FCWs + ch * 29;
    float acc = fcb[ch];
#pragma unroll
    for (int u = 0; u < 24; ++u) acc = fmaf(mm[u], wr[u], acc);
    out[ob + ch * 4096] = acc;
  }
}

extern "C" void kernel_launch(void* const* d_in, const int* in_sizes, int n_in,
                              void* d_out, int out_size, void* d_ws, size_t ws_size,
                              hipStream_t stream) {
  const float* x      = (const float*)d_in[0];
  const float* conv_w = (const float*)d_in[1];
  const float* conv_b = (const float*)d_in[2];
  const float* u3p    = (const float*)d_in[3];
  const float* cu3p   = (const float*)d_in[4];
  const float* fcw    = (const float*)d_in[5];
  const float* fcb    = (const float*)d_in[6];
  float* out = (float*)d_out;

  qconv_kernel<<<512, 256, 0, stream>>>(x, conv_w, conv_b, u3p, cu3p,
                                        fcw, fcb, out);
}

// Round 10
// 105.700 us; speedup vs baseline: 1.0977x; 1.0977x over previous
//
#include <hip/hip_runtime.h>

typedef float v2f __attribute__((ext_vector_type(2)));
typedef float v4f __attribute__((ext_vector_type(4)));

// ---------------------------------------------------------------------------
// Layout (8 px/wave): group g = lane>>4 holds the packed pixel pair in v2f.
// Amp i = q*16 + r, q = lane&15, r = 0..15. Wires 0..3 <-> q bits 3..0
// (masks 8,4,2,1); wires 4..7 <-> r bits 3..0.
// FINAL (= R8, session best: 50.9-51.4us dispatch, verified):
//  - per-lane-permuted gate tables (one ds_read_b128 per cross stage, no
//    cndmask selection chains) [R6]
//  - coefficient reads software-pipelined one block ahead through NAMED v4f
//    values (SROA-safe; arrays spill to scratch) [R7]
//  - conv boundary math hoisted; f8p split by r-parity [R8]
//  - DPP-only butterflies (xor4 = row_half_mirror o quad_perm) [R4]
//  - FC weights stride-29 in LDS (conflict-free) [R4]
// Tripwires for any future edit: WRITE_SIZE must stay 2048 (scratch),
// absmax 0.00195 (fp path), VGPR <= ~128.
// ---------------------------------------------------------------------------
template<int C>
__device__ __forceinline__ float dppmov(float x) {
  return __int_as_float(__builtin_amdgcn_update_dpp(0, __float_as_int(x), C, 0xF, 0xF, true));
}
__device__ __forceinline__ float bperm(float x, int a) {
  return __int_as_float(__builtin_amdgcn_ds_bpermute(a, __float_as_int(x)));
}
template<int M>
__device__ __forceinline__ float bfly(float x) {
  if constexpr (M == 1)      return dppmov<0xB1>(x);   // quad_perm [1,0,3,2]
  else if constexpr (M == 2) return dppmov<0x4E>(x);   // quad_perm [2,3,0,1]
  else if constexpr (M == 3) return dppmov<0x1B>(x);   // quad_perm [3,2,1,0]
  else if constexpr (M == 8) return dppmov<0x128>(x);  // row_ror:8 == xor8
  else                       return dppmov<0x1B>(dppmov<0x141>(x)); // xor4 = xor7 o xor3
}
template<int M>
__device__ __forceinline__ v2f bfly2(v2f v) {
  v2f o; o.x = bfly<M>(v.x); o.y = bfly<M>(v.y); return o;
}
__device__ __forceinline__ v2f sp(float s) { v2f v; v.x = s; v.y = s; return v; }
__device__ __forceinline__ v2f vfma(v2f a, v2f b, v2f c) {
  return __builtin_elementwise_fma(a, b, c);
}

// ---------------------------------------------------------------------------
// Gate stages (16 state regs). Coefficients arrive as v4f VALUES.
// ---------------------------------------------------------------------------
template<int M>
__device__ __forceinline__ void crossGv(v2f Sr[16], v2f Si[16], v4f c) {
  v2f vfr = sp(c.x), vfi = sp(c.y), vgr = sp(c.z), vgi = sp(c.w);
  v2f vfiN = sp(-c.y), vgiN = sp(-c.w);
#pragma unroll
  for (int r = 0; r < 16; ++r) {
    v2f pR = bfly2<M>(Sr[r]);
    v2f pI = bfly2<M>(Si[r]);
    v2f nR = vfma(vgiN, pI, vfma(vgr, pR, vfma(vfiN, Si[r], vfr * Sr[r])));
    v2f nI = vfma(vgi,  pR, vfma(vgr, pI, vfma(vfi,  Sr[r], vfr * Si[r])));
    Sr[r] = nR; Si[r] = nI;
  }
}

__device__ __forceinline__ void mixP(v2f& x0r, v2f& x0i, v2f& x1r, v2f& x1i,
    float m0r, float m0i, float m1r, float m1i,
    float m2r, float m2i, float m3r, float m3i) {
  v2f n0r = vfma(sp(-m1i), x1i, vfma(sp(m1r), x1r, vfma(sp(-m0i), x0i, sp(m0r) * x0r)));
  v2f n0i = vfma(sp( m1i), x1r, vfma(sp(m1r), x1i, vfma(sp( m0i), x0r, sp(m0r) * x0i)));
  v2f n1r = vfma(sp(-m3i), x1i, vfma(sp(m3r), x1r, vfma(sp(-m2i), x0i, sp(m2r) * x0r)));
  v2f n1i = vfma(sp( m3i), x1r, vfma(sp(m3r), x1i, vfma(sp( m2i), x0r, sp(m2r) * x0i)));
  x0r = n0r; x0i = n0i; x1r = n1r; x1i = n1i;
}

// F4: fused u3(w4)+cu3(3->4): ctrl lane bit0 (baked into address), tgt r bit3.
__device__ __forceinline__ void f4Nv(v2f Sr[16], v2f Si[16], v4f A, v4f B) {
#pragma unroll
  for (int r = 0; r < 8; ++r)
    mixP(Sr[r], Si[r], Sr[r + 8], Si[r + 8],
         A.x, A.y, A.z, A.w, B.x, B.y, B.z, B.w);
}
// F5: ctrl r bit3, target r bit2 (uniform; coeffs pre-loaded by caller).
__device__ __forceinline__ void f5v(v2f Sr[16], v2f Si[16],
    v4f A, v4f B, v4f C, v4f D) {
#pragma unroll
  for (int r = 0; r < 4; ++r)
    mixP(Sr[r], Si[r], Sr[r + 4], Si[r + 4],
         A.x, A.y, A.z, A.w, B.x, B.y, B.z, B.w);
#pragma unroll
  for (int r = 8; r < 12; ++r)
    mixP(Sr[r], Si[r], Sr[r + 4], Si[r + 4],
         C.x, C.y, C.z, C.w, D.x, D.y, D.z, D.w);
}

// One row of the F67 4x4: d = M[row] . a, M row = {a.x..a.w, b.x..b.w}.
__device__ __forceinline__ void f67row(v2f& dR, v2f& dI, v4f a, v4f b,
    v2f ar0, v2f ai0, v2f ar1, v2f ai1,
    v2f ar2, v2f ai2, v2f ar3, v2f ai3) {
  v2f nR = sp(a.x) * ar0;
  nR = vfma(sp(-a.y), ai0, nR);
  nR = vfma(sp( a.z), ar1, nR);
  nR = vfma(sp(-a.w), ai1, nR);
  nR = vfma(sp( b.x), ar2, nR);
  nR = vfma(sp(-b.y), ai2, nR);
  nR = vfma(sp( b.z), ar3, nR);
  nR = vfma(sp(-b.w), ai3, nR);
  v2f nI = sp(a.y) * ar0;
  nI = vfma(sp(a.x), ai0, nI);
  nI = vfma(sp(a.w), ar1, nI);
  nI = vfma(sp(a.z), ai1, nI);
  nI = vfma(sp(b.y), ar2, nI);
  nI = vfma(sp(b.x), ai2, nI);
  nI = vfma(sp(b.w), ar3, nI);
  nI = vfma(sp(b.z), ai3, nI);
  dR = nR; dI = nI;
}
// F67 4x4 on one reg-quad at base B; rows (m0a,m0b)..(m3a,m3b).
__device__ __forceinline__ void f67q(v2f* Sr, v2f* Si, int B,
    v4f m0a, v4f m0b, v4f m1a, v4f m1b,
    v4f m2a, v4f m2b, v4f m3a, v4f m3b) {
  v2f ar0 = Sr[B+0], ai0 = Si[B+0], ar1 = Sr[B+1], ai1 = Si[B+1];
  v2f ar2 = Sr[B+2], ai2 = Si[B+2], ar3 = Sr[B+3], ai3 = Si[B+3];
  f67row(Sr[B+0], Si[B+0], m0a, m0b, ar0, ai0, ar1, ai1, ar2, ai2, ar3, ai3);
  f67row(Sr[B+1], Si[B+1], m1a, m1b, ar0, ai0, ar1, ai1, ar2, ai2, ar3, ai3);
  f67row(Sr[B+2], Si[B+2], m2a, m2b, ar0, ai0, ar1, ai1, ar2, ai2, ar3, ai3);
  f67row(Sr[B+3], Si[B+3], m3a, m3b, ar0, ai0, ar1, ai1, ar2, ai2, ar3, ai3);
}

// F8': fused cu3(7->0)+next u3(w0): ctrl r bit0, target mask 8.
// Split by r-parity: even r uses A, odd r uses B -- no per-r selects.
__device__ __forceinline__ void f8pNv(v2f Sr[16], v2f Si[16], v4f A, v4f B) {
  {
    v2f fr = sp(A.x), fi = sp(A.y), gr = sp(A.z), gi = sp(A.w);
    v2f fiN = sp(-A.y), giN = sp(-A.w);
#pragma unroll
    for (int r = 0; r < 16; r += 2) {
      v2f pR = bfly2<8>(Sr[r]);
      v2f pI = bfly2<8>(Si[r]);
      v2f nR = vfma(giN, pI, vfma(gr, pR, vfma(fiN, Si[r], fr * Sr[r])));
      v2f nI = vfma(gi,  pR, vfma(gr, pI, vfma(fi,  Sr[r], fr * Si[r])));
      Sr[r] = nR; Si[r] = nI;
    }
  }
  {
    v2f fr = sp(B.x), fi = sp(B.y), gr = sp(B.z), gi = sp(B.w);
    v2f fiN = sp(-B.y), giN = sp(-B.w);
#pragma unroll
    for (int r = 1; r < 16; r += 2) {
      v2f pR = bfly2<8>(Sr[r]);
      v2f pI = bfly2<8>(Si[r]);
      v2f nR = vfma(giN, pI, vfma(gr, pR, vfma(fiN, Si[r], fr * Sr[r])));
      v2f nI = vfma(gi,  pR, vfma(gr, pI, vfma(fi,  Sr[r], fr * Si[r])));
      Sr[r] = nR; Si[r] = nI;
    }
  }
}
// F8 final standalone cu3(7->0): odd r only, target mask 8.
__device__ __forceinline__ void f8Nv(v2f Sr[16], v2f Si[16], v4f c) {
  v2f vfr = sp(c.x), vfi = sp(c.y), vgr = sp(c.z), vgi = sp(c.w);
  v2f vfiN = sp(-c.y), vgiN = sp(-c.w);
#pragma unroll
  for (int r = 1; r < 16; r += 2) {
    v2f pR = bfly2<8>(Sr[r]);
    v2f pI = bfly2<8>(Si[r]);
    v2f nR = vfma(vgiN, pI, vfma(vgr, pR, vfma(vfiN, Si[r], vfr * Sr[r])));
    v2f nI = vfma(vgi,  pR, vfma(vgr, pI, vfma(vfi,  Sr[r], vfr * Si[r])));
    Sr[r] = nR; Si[r] = nI;
  }
}

// Off-diagonal pair sum for a cross wire (mask M): per-lane partials.
template<int M>
__device__ __forceinline__ void crossO(const v2f Sr[16], const v2f Si[16],
                                       v2f& re, v2f& im) {
  v2f r = sp(0.0f), i = sp(0.0f);
#pragma unroll
  for (int k = 0; k < 16; ++k) {
    v2f pr = bfly2<M>(Sr[k]);
    v2f pi = bfly2<M>(Si[k]);
    r = vfma(Sr[k], pr, r);
    r = vfma(Si[k], pi, r);
    i = vfma(Si[k], pr, i);
    i = vfma(-Sr[k], pi, i);
  }
  re = r; im = i;
}

// ---------------------------------------------------------------------------
// Prep helpers.
// ---------------------------------------------------------------------------
__device__ __forceinline__ void mm2(const float* A, const float* B, float* D) {
  D[0] = A[0]*B[0] - A[1]*B[1] + A[2]*B[4] - A[3]*B[5];
  D[1] = A[0]*B[1] + A[1]*B[0] + A[2]*B[5] + A[3]*B[4];
  D[2] = A[0]*B[2] - A[1]*B[3] + A[2]*B[6] - A[3]*B[7];
  D[3] = A[0]*B[3] + A[1]*B[2] + A[2]*B[7] + A[3]*B[6];
  D[4] = A[4]*B[0] - A[5]*B[1] + A[6]*B[4] - A[7]*B[5];
  D[5] = A[4]*B[1] + A[5]*B[0] + A[6]*B[5] + A[7]*B[4];
  D[6] = A[4]*B[2] - A[5]*B[3] + A[6]*B[6] - A[7]*B[7];
  D[7] = A[4]*B[3] + A[5]*B[2] + A[6]*B[7] + A[7]*B[6];
}
__device__ __forceinline__ void u3fill(const float* src, float* o) {
  float th = src[0], ph = src[1], lam = src[2];
  float c = cosf(0.5f * th), s = sinf(0.5f * th);
  float cl = cosf(lam), sl = sinf(lam);
  float cp = cosf(ph), spv = sinf(ph);
  float cpl = cosf(ph + lam), spl = sinf(ph + lam);
  o[0] = c;        o[1] = 0.0f;
  o[2] = -cl * s;  o[3] = -sl * s;
  o[4] = cp * s;   o[5] = spv * s;
  o[6] = cpl * c;  o[7] = spl * c;
}

// ---------------------------------------------------------------------------
// Single fused kernel. Gp layout (per block b, stride 80 floats):
//   +0  F1 [sel=ct*2+hi][4]={fr,fi,gr,gi}; +16 F2; +32 F3
//   +48 F4 [ct][8]; +64 F8' [hi][8]. Final F8 at Gp+400: [hi][4].
// ---------------------------------------------------------------------------
__global__ __launch_bounds__(256, 2) void qconv_kernel(
    const float* __restrict__ x, const float* __restrict__ cw,
    const float* __restrict__ cb, const float* __restrict__ u3p,
    const float* __restrict__ cu3p, const float* __restrict__ fcw,
    const float* __restrict__ fcb, float* __restrict__ out) {
  __shared__ float Us[40][8];
  __shared__ float Cs[40][8];
  __shared__ __attribute__((aligned(16))) float Gs[640];
  __shared__ float FCWs[32 * 29];   // stride 29: odd*4 bank step, conflict-free
  __shared__ __attribute__((aligned(16))) float F67t[320];
  __shared__ __attribute__((aligned(16))) float Gp[408];

  // ---- in-block prep ----
  {
    const int t = threadIdx.x;
    if (t < 40) u3fill(u3p + t * 3, Us[t]);
    if (t >= 64 && t < 104) u3fill(cu3p + (t - 64) * 3, Cs[t - 64]);
    for (int i = t; i < 32 * 29; i += 256) {
      int ch = i / 29, u = i - ch * 29;
      float v = 0.0f;
      if (u < 24) {
        float sc = (u >= 8 && (u & 7) >= 4) ? 2.0f : 1.0f;
        v = fcw[ch * 24 + u] * sc;
      }
      FCWs[i] = v;
    }
    __syncthreads();
    if (t == 0) {
#pragma unroll
      for (int j = 0; j < 8; ++j) Gs[j] = Us[0][j];
    } else if (t < 36) {
      int j = t - 1, b = j / 7, k = j % 7;
      float* dst = Gs + 8 + b * 112 + k * 16;
      const float* U = Us[b * 8 + k + 1];
      const float* C = Cs[b * 8 + k];
#pragma unroll
      for (int u = 0; u < 8; ++u) dst[u] = U[u];
      mm2(C, U, dst + 8);
    } else if (t < 40) {
      int b = t - 36;
      float* dst = Gs + 568 + b * 16;
      const float* U = Us[(b + 1) * 8];
      const float* C = Cs[b * 8 + 7];
#pragma unroll
      for (int u = 0; u < 8; ++u) dst[u] = U[u];
      mm2(U, C, dst + 8);
    } else if (t == 40) {
#pragma unroll
      for (int j = 0; j < 8; ++j) Gs[632 + j] = Cs[39][j];
    }
    __syncthreads();
    // F67 fused tables + per-lane table permute (disjoint thread ranges)
    if (t < 60) {
      // crossG entries: 5 blocks x 3 stages x 4 sels
      int b = t / 12, rem = t % 12;
      int st = rem >> 2, sel = rem & 3;
      int hi = sel & 1, ct = sel >> 1;
      const float* src = Gs + 8 + b * 112 + st * 16 + (ct ? 8 : 0);
      float* dst = Gp + b * 80 + st * 16 + sel * 4;
      dst[0] = src[hi ? 6 : 0]; dst[1] = src[hi ? 7 : 1];
      dst[2] = src[hi ? 4 : 2]; dst[3] = src[hi ? 5 : 3];
    } else if (t >= 64 && t < 104) {
      int u = t - 64;
      int b = u >> 3, idx = u & 7;
      int ct = idx >> 2, rp = idx & 3;
      const float* M6 = Gs + 8 + b * 112 + 80 + ct * 8;
      int b1p = rp >> 1, b0p = rp & 1;
      const float* M7 = Gs + 8 + b * 112 + 96 + b1p * 8;
      float* dst = F67t + b * 64 + ct * 32 + rp * 8;
#pragma unroll
      for (int c = 0; c < 4; ++c) {
        int b1 = c >> 1, b0 = c & 1;
        float a_r = M6[(b1p * 2 + b1) * 2], a_i = M6[(b1p * 2 + b1) * 2 + 1];
        float b_r = M7[(b0p * 2 + b0) * 2], b_i = M7[(b0p * 2 + b0) * 2 + 1];
        dst[c * 2]     = a_r * b_r - a_i * b_i;
        dst[c * 2 + 1] = a_r * b_i + a_i * b_r;
      }
    } else if (t >= 192 && t < 202) {
      // F4 copy: 5 blocks x 2 ct halves
      int u = t - 192, b = u >> 1, ct = u & 1;
      const float* src = Gs + 8 + b * 112 + 48 + ct * 8;
      float* dst = Gp + b * 80 + 48 + ct * 8;
#pragma unroll
      for (int j = 0; j < 8; ++j) dst[j] = src[j];
    } else if (t >= 208 && t < 216) {
      // F8' entries: 4 blocks x 2 hi
      int u = t - 208, b = u >> 1, hi = u & 1;
      const float* src = Gs + 568 + b * 16;
      float* dst = Gp + b * 80 + 64 + hi * 8;
      dst[0] = src[hi ? 6 : 0];     dst[1] = src[hi ? 7 : 1];
      dst[2] = src[hi ? 4 : 2];     dst[3] = src[hi ? 5 : 3];
      dst[4] = src[8 + (hi ? 6 : 0)]; dst[5] = src[8 + (hi ? 7 : 1)];
      dst[6] = src[8 + (hi ? 4 : 2)]; dst[7] = src[8 + (hi ? 5 : 3)];
    } else if (t >= 216 && t < 218) {
      // F8 final: 2 hi entries
      int hi = t - 216;
      const float* src = Gs + 632;
      float* dst = Gp + 400 + hi * 4;
      dst[0] = src[hi ? 6 : 0]; dst[1] = src[hi ? 7 : 1];
      dst[2] = src[hi ? 4 : 2]; dst[3] = src[hi ? 5 : 3];
    }
    __syncthreads();
  }

  const int lane = threadIdx.x & 63;
  const int wid = __builtin_amdgcn_readfirstlane(
      (int)((blockIdx.x * blockDim.x + threadIdx.x) >> 6));
  const int p0 = wid * 8;
  const int q = lane & 15;

  // ---- conv: lane = (px = lane>>3, oc = lane&7); boundary math hoisted ----
  float ang;
  {
    const int px = lane >> 3;
    const int oc = lane & 7;
    const int p  = p0 + px;
    const int b  = p >> 12;
    const int hh = (p >> 6) & 63;
    const int wim = p & 63;
    int offs[9];
    float okf[9];
#pragma unroll
    for (int kh = 0; kh < 3; ++kh) {
      int ih = hh + kh - 1;
      bool rok = (unsigned)ih < 64u;
      int ihc = rok ? ih : 0;
#pragma unroll
      for (int kw = 0; kw < 3; ++kw) {
        int iw = wim + kw - 1;
        bool ok = rok && ((unsigned)iw < 64u);
        int iwc = ((unsigned)iw < 64u) ? iw : 0;
        offs[kh * 3 + kw] = ihc * 64 + iwc;
        okf[kh * 3 + kw] = ok ? 1.0f : 0.0f;
      }
    }
    float acc = cb[oc];
    const float* wp0 = cw + oc * 144;
    const float* xp0 = x + b * 65536;
#pragma unroll 4
    for (int ic = 0; ic < 16; ++ic) {
      const float* wp = wp0 + ic * 9;
      const float* xp = xp0 + ic * 4096;
#pragma unroll
      for (int j = 0; j < 9; ++j)
        acc = fmaf(xp[offs[j]] * okf[j], wp[j], acc);
    }
    ang = acc;
  }

  // ---- gather 16 angles, build product state with F0 folded ----
  v2f Sr[16], Si[16];
  {
    const int gb = (lane & 48) << 2;
    float aA[8], aB[8];
#pragma unroll
    for (int w = 0; w < 8; ++w) {
      aA[w] = bperm(ang, gb + (w << 2));
      aB[w] = bperm(ang, gb + ((8 + w) << 2));
    }
    float cA[8], sA[8], cB[8], sB[8];
#pragma unroll
    for (int w = 0; w < 8; ++w) {
      __sincosf(0.5f * aA[w], &sA[w], &cA[w]);
      __sincosf(0.5f * aB[w], &sB[w], &cB[w]);
    }
    v2f c0; c0.x = cA[0]; c0.y = cB[0];
    v2f s0; s0.x = sA[0]; s0.y = sB[0];
    v2f c0r = vfma(sp(Gs[2]), s0, sp(Gs[0]) * c0);
    v2f c0i = vfma(sp(Gs[3]), s0, sp(Gs[1]) * c0);
    v2f s0r = vfma(sp(Gs[6]), s0, sp(Gs[4]) * c0);
    v2f s0i = vfma(sp(Gs[7]), s0, sp(Gs[5]) * c0);
    const bool w0 = (q & 8) != 0;
    v2f selR = w0 ? s0r : c0r;
    v2f selI = w0 ? s0i : c0i;
    float fA = ((q & 4) ? sA[1] : cA[1]) * ((q & 2) ? sA[2] : cA[2])
             * ((q & 1) ? sA[3] : cA[3]);
    float fB = ((q & 4) ? sB[1] : cB[1]) * ((q & 2) ? sB[2] : cB[2])
             * ((q & 1) ? sB[3] : cB[3]);
    v2f uu[4], vv[4];
    uu[0].x = cA[6]*cA[7]; uu[1].x = cA[6]*sA[7];
    uu[2].x = sA[6]*cA[7]; uu[3].x = sA[6]*sA[7];
    uu[0].y = cB[6]*cB[7]; uu[1].y = cB[6]*sB[7];
    uu[2].y = sB[6]*cB[7]; uu[3].y = sB[6]*sB[7];
    float vA0 = fA * cA[4], vA1 = fA * sA[4];
    float vB0 = fB * cB[4], vB1 = fB * sB[4];
    vv[0].x = vA0*cA[5]; vv[1].x = vA0*sA[5];
    vv[2].x = vA1*cA[5]; vv[3].x = vA1*sA[5];
    vv[0].y = vB0*cB[5]; vv[1].y = vB0*sB[5];
    vv[2].y = vB1*cB[5]; vv[3].y = vB1*sB[5];
#pragma unroll
    for (int r = 0; r < 16; ++r) {
      v2f base = vv[r >> 2] * uu[r & 3];
      Sr[r] = selR * base;
      Si[r] = selI * base;
    }
  }

  // ---- fused circuit: pipelined per-lane coefficient reads ----
  {
    const int s1 = ((lane & 8) ? 2 : 0) | ((lane & 4) ? 1 : 0);
    const int s2 = ((lane & 4) ? 2 : 0) | ((lane & 2) ? 1 : 0);
    const int s3 = ((lane & 2) ? 2 : 0) | ((lane & 1) ? 1 : 0);
    const float* pF1 = Gp + s1 * 4;
    const float* pF2 = Gp + 16 + s2 * 4;
    const float* pF3 = Gp + 32 + s3 * 4;
    const float* pF4 = Gp + 48 + (lane & 1) * 8;
    const float* pF8 = Gp + 64 + ((lane & 8) ? 8 : 0);
    // prologue: block-0 per-lane coeffs
    v4f k1 = *(const v4f*)pF1;
    v4f k2 = *(const v4f*)pF2;
    v4f k3 = *(const v4f*)pF3;
    v4f k4a = *(const v4f*)pF4,      k4b = *(const v4f*)(pF4 + 4);
    v4f k8a = *(const v4f*)pF8,      k8b = *(const v4f*)(pF8 + 4);
    for (int b = 0; b < 5; ++b) {
      const int o = b * 80;
      // uniform tables for THIS block
      const v4f* f5p = (const v4f*)(Gs + 8 + b * 112 + 64);
      v4f f5A = f5p[0], f5B = f5p[1], f5C = f5p[2], f5D = f5p[3];
      const v4f* Tp = (const v4f*)(F67t + b * 64);
      v4f t0 = Tp[0],  t1 = Tp[1],  t2 = Tp[2],  t3 = Tp[3];
      v4f t4 = Tp[4],  t5 = Tp[5],  t6 = Tp[6],  t7 = Tp[7];
      v4f t8 = Tp[8],  t9 = Tp[9],  t10 = Tp[10], t11 = Tp[11];
      v4f t12 = Tp[12], t13 = Tp[13], t14 = Tp[14], t15 = Tp[15];
      // NEXT block's per-lane coeffs (clamped offset on last iter; values
      // from the clamp are never consumed)
      const int no = (b < 4) ? o + 80 : o;
      v4f n1 = *(const v4f*)(pF1 + no);
      v4f n2 = *(const v4f*)(pF2 + no);
      v4f n3 = *(const v4f*)(pF3 + no);
      v4f n4a = *(const v4f*)(pF4 + no), n4b = *(const v4f*)(pF4 + no + 4);
      v4f n8a = *(const v4f*)(pF8 + no), n8b = *(const v4f*)(pF8 + no + 4);

      crossGv<4>(Sr, Si, k1);                    // F1: tgt w1(m4)
      crossGv<2>(Sr, Si, k2);                    // F2: tgt w2(m2)
      crossGv<1>(Sr, Si, k3);                    // F3: tgt w3(m1)
      f4Nv(Sr, Si, k4a, k4b);                    // F4: tgt r3
      f5v(Sr, Si, f5A, f5B, f5C, f5D);           // F5: tgt r2
      f67q(Sr, Si, 0,  t0, t1, t2,  t3,  t4,  t5,  t6,  t7);
      f67q(Sr, Si, 4,  t8, t9, t10, t11, t12, t13, t14, t15);
      f67q(Sr, Si, 8,  t0, t1, t2,  t3,  t4,  t5,  t6,  t7);
      f67q(Sr, Si, 12, t8, t9, t10, t11, t12, t13, t14, t15);
      if (b < 4) f8pNv(Sr, Si, k8a, k8b);        // F8': tgt m8, ctrl r0
      k1 = n1; k2 = n2; k3 = n3; k4a = n4a; k4b = n4b; k8a = n8a; k8b = n8b;
    }
    f8Nv(Sr, Si, *(const v4f*)(Gp + 400 + ((lane & 8) ? 4 : 0)));
  }

  // ---- per-lane measurement partials ----
  float sg[4];
  sg[0] = (q & 8) ? -1.0f : 1.0f;
  sg[1] = (q & 4) ? -1.0f : 1.0f;
  sg[2] = (q & 2) ? -1.0f : 1.0f;
  sg[3] = (q & 1) ? -1.0f : 1.0f;

  v2f PT[24];
  {
    v2f re0, im0, re1, im1, re2, im2, re3, im3;
    crossO<8>(Sr, Si, re0, im0);
    crossO<4>(Sr, Si, re1, im1);
    crossO<2>(Sr, Si, re2, im2);
    crossO<1>(Sr, Si, re3, im3);
    PT[8]  = re0; PT[9]  = re1; PT[10] = re2; PT[11] = re3;
    PT[16] = sp(sg[0]) * im0; PT[17] = sp(sg[1]) * im1;
    PT[18] = sp(sg[2]) * im2; PT[19] = sp(sg[3]) * im3;

    v2f P[16];
#pragma unroll
    for (int r = 0; r < 16; ++r) P[r] = vfma(Si[r], Si[r], Sr[r] * Sr[r]);
    v2f t01[8];
#pragma unroll
    for (int k = 0; k < 8; ++k) t01[k] = P[2*k] + P[2*k+1];
    v2f q0 = t01[0] + t01[1], q1 = t01[2] + t01[3];
    v2f q2 = t01[4] + t01[5], q3 = t01[6] + t01[7];
    v2f h0 = q0 + q1, h1 = q2 + q3;
    v2f p  = h0 + h1;
    PT[4] = h0 - h1;
    PT[5] = (q0 - q1) + (q2 - q3);
    PT[6] = (t01[0]-t01[1]) + (t01[2]-t01[3])
          + (t01[4]-t01[5]) + (t01[6]-t01[7]);
    PT[7] = (P[0]-P[1]) + (P[2]-P[3]) + (P[4]-P[5]) + (P[6]-P[7])
          + (P[8]-P[9]) + (P[10]-P[11]) + (P[12]-P[13]) + (P[14]-P[15]);
    PT[0] = sp(sg[0]) * p; PT[1] = sp(sg[1]) * p;
    PT[2] = sp(sg[2]) * p; PT[3] = sp(sg[3]) * p;

    v2f re, im;
    re = sp(0.0f); im = sp(0.0f);
#pragma unroll
    for (int r = 0; r < 8; ++r) {
      re = vfma(Sr[r], Sr[r+8], re); re = vfma(Si[r], Si[r+8], re);
      im = vfma(Si[r], Sr[r+8], im); im = vfma(-Sr[r], Si[r+8], im);
    }
    PT[12] = re; PT[20] = im;
    re = sp(0.0f); im = sp(0.0f);
#pragma unroll
    for (int t = 0; t < 8; ++t) {
      const int lo = (t & 3) + (t >> 2) * 8;
      re = vfma(Sr[lo], Sr[lo+4], re); re = vfma(Si[lo], Si[lo+4], re);
      im = vfma(Si[lo], Sr[lo+4], im); im = vfma(-Sr[lo], Si[lo+4], im);
    }
    PT[13] = re; PT[21] = im;
    re = sp(0.0f); im = sp(0.0f);
#pragma unroll
    for (int t = 0; t < 8; ++t) {
      const int lo = (t & 1) + (t >> 1) * 4;
      re = vfma(Sr[lo], Sr[lo+2], re); re = vfma(Si[lo], Si[lo+2], re);
      im = vfma(Si[lo], Sr[lo+2], im); im = vfma(-Sr[lo], Si[lo+2], im);
    }
    PT[14] = re; PT[22] = im;
    re = sp(0.0f); im = sp(0.0f);
#pragma unroll
    for (int t = 0; t < 8; ++t) {
      const int lo = 2 * t;
      re = vfma(Sr[lo], Sr[lo+1], re); re = vfma(Si[lo], Si[lo+1], re);
      im = vfma(Si[lo], Sr[lo+1], im); im = vfma(-Sr[lo], Si[lo+1], im);
    }
    PT[15] = re; PT[23] = im;
  }

  // ---- group-reduce partials to uniform values, THEN per-channel FC ----
  const int j = q & 7;
  const bool isB = (q & 8) != 0;
  float mm[24];
#pragma unroll
  for (int t = 0; t < 24; ++t) {
    v2f v = PT[t] + bfly2<8>(PT[t]);   // pair over mask 8 (both pixels)
    float s = isB ? v.y : v.x;          // keep own pixel
    s += bfly<1>(s);
    s += bfly<2>(s);
    s += bfly<4>(s);                    // completes the 16-lane sum
    mm[t] = s;
  }

  const int g = lane >> 4;
  const int p = p0 + 2 * g + (isB ? 1 : 0);
  const int ob = (p >> 12) * 131072 + (p & 4095);
#pragma unroll
  for (int k = 0; k < 4; ++k) {
    const int ch = 4 * j + k;
    const float* wr = FCWs + ch * 29;
    float acc = fcb[ch];
#pragma unroll
    for (int u = 0; u < 24; ++u) acc = fmaf(mm[u], wr[u], acc);
    out[ob + ch * 4096] = acc;
  }
}

extern "C" void kernel_launch(void* const* d_in, const int* in_sizes, int n_in,
                              void* d_out, int out_size, void* d_ws, size_t ws_size,
                              hipStream_t stream) {
  const float* x      = (const float*)d_in[0];
  const float* conv_w = (const float*)d_in[1];
  const float* conv_b = (const float*)d_in[2];
  const float* u3p    = (const float*)d_in[3];
  const float* cu3p   = (const float*)d_in[4];
  const float* fcw    = (const float*)d_in[5];
  const float* fcb    = (const float*)d_in[6];
  float* out = (float*)d_out;

  qconv_kernel<<<512, 256, 0, stream>>>(x, conv_w, conv_b, u3p, cu3p,
                                        fcw, fcb, out);
}